// Round 2
// baseline (289.035 us; speedup 1.0000x reference)
//
#include <hip/hip_runtime.h>
#include <hip/hip_bf16.h>

typedef unsigned short u16;
typedef unsigned int   u32;
typedef unsigned long long u64;
typedef __bf16 bf16x8 __attribute__((ext_vector_type(8)));
typedef float  f32x4  __attribute__((ext_vector_type(4)));

#define S_LEN  2048
#define BATCH  2
#define DMODEL 1024
#define NHEADS 16
#define DKH    64
#define MWORDS (S_LEN/64)
#define ATT_SCALE 0.125f

__device__ __forceinline__ u16 f2bf(float f){
  u32 x = __builtin_bit_cast(u32, f);
  x += 0x7fffu + ((x >> 16) & 1u);   // RNE
  return (u16)(x >> 16);
}
__device__ __forceinline__ bf16x8 ld8(const u16* p){ return *(const bf16x8*)p; }

// async global->LDS, 16B per lane. HW: dest = wave-uniform base + lane*16.
__device__ __forceinline__ void gload16(const u16* g, u16* l){
  __builtin_amdgcn_global_load_lds(
      (const __attribute__((address_space(1))) u32*)(u64)g,
      (__attribute__((address_space(3))) u32*)(u64)l,
      16, 0, 0);
}

// ---- fp32->bf16 bulk conversion + mask bit-packing ----
// NEW this round: mask packing unrolled 4x — four independent coalesced dword
// loads in flight per wave-iteration (was a serial load->ballot->store chain).
// Ballot semantics unchanged.
__global__ __launch_bounds__(256) void cvt_kernel(
    const float* __restrict__ a0, const float* __restrict__ a1, const float* __restrict__ a2,
    const float* __restrict__ wi, const float* __restrict__ wo, const int* __restrict__ msk,
    u16* __restrict__ d0, u16* __restrict__ d1, u16* __restrict__ d2,
    u16* __restrict__ dwi, u16* __restrict__ dwo, u64* __restrict__ mbits)
{
  int tid = blockIdx.x*256 + threadIdx.x;
  int stride = gridDim.x*256;
  const int NX = S_LEN*BATCH*DMODEL/4;
  for (int i = tid; i < NX; i += stride){
    f32x4 x0 = ((const f32x4*)a0)[i];
    f32x4 x1 = ((const f32x4*)a1)[i];
    f32x4 x2 = ((const f32x4*)a2)[i];
    ((ushort4*)d0)[i] = make_ushort4(f2bf(x0[0]), f2bf(x0[1]), f2bf(x0[2]), f2bf(x0[3]));
    ((ushort4*)d1)[i] = make_ushort4(f2bf(x1[0]), f2bf(x1[1]), f2bf(x1[2]), f2bf(x1[3]));
    ((ushort4*)d2)[i] = make_ushort4(f2bf(x2[0]), f2bf(x2[1]), f2bf(x2[2]), f2bf(x2[3]));
  }
  const int NWI = 3*DMODEL*DMODEL/4;
  for (int i = tid; i < NWI; i += stride){
    f32x4 x = ((const f32x4*)wi)[i];
    ((ushort4*)dwi)[i] = make_ushort4(f2bf(x[0]), f2bf(x[1]), f2bf(x[2]), f2bf(x[3]));
  }
  const int NWO = DMODEL*DMODEL/4;
  for (int i = tid; i < NWO; i += stride){
    f32x4 x = ((const f32x4*)wo)[i];
    ((ushort4*)dwo)[i] = make_ushort4(f2bf(x[0]), f2bf(x[1]), f2bf(x[2]), f2bf(x[3]));
  }
  int gw   = tid >> 6;
  int lane = threadIdx.x & 63;
  int nwaves = stride >> 6;
  const int NW = BATCH*S_LEN*MWORDS;
  for (int w4 = gw*4; w4 < NW; w4 += nwaves*4){
    int v0 = msk[(size_t)(w4+0)*64 + lane];
    int v1 = msk[(size_t)(w4+1)*64 + lane];
    int v2 = msk[(size_t)(w4+2)*64 + lane];
    int v3 = msk[(size_t)(w4+3)*64 + lane];
    u64 b0 = __ballot(v0 != 0);
    u64 b1 = __ballot(v1 != 0);
    u64 b2 = __ballot(v2 != 0);
    u64 b3 = __ballot(v3 != 0);
    if (lane == 0){
      mbits[w4+0] = b0; mbits[w4+1] = b1;
      mbits[w4+2] = b2; mbits[w4+3] = b3;
    }
  }
}

// ---- 128x128 block GEMM mainloop (C = A @ W^T), K = DMODEL ----
// 2-phase LDS double-buffer (T3-minimum recipe, +10% attested m248v2).
// Per K-step: issue next tile's global_load_lds into buf^1 BEFORE computing
// buf, then ONE __syncthreads (its vmcnt(0)+lgkmcnt(0) drain makes the next
// buffer visible and proves this buffer's ds_reads are done before overwrite).
// abuf/bbuf are each 2*128*32 u16 (16 KB); 32 KB LDS total -> 5 blocks/CU cap.
// XOR chunk swizzle on the *global* source unchanged; fragment layouts
// unchanged (m89/m91); C/D: lane reg -> D[quad*4+reg][r].
__device__ __forceinline__ void gemm128_loop(
    const u16* __restrict__ A, const u16* __restrict__ W,
    u16* abuf, u16* bbuf, int tid, f32x4 acc[4][4])
{
  int lane = tid & 63, quad = lane >> 4, r = lane & 15;
  int wv = tid >> 6, wm = (wv & 1)*64, wn = (wv >> 1)*64;
  int c0 = tid, c1 = tid + 256;              // 16B-chunk ids (512 per tile)
  int r0 = c0 >> 2, g0 = ((c0 & 3) ^ (r0 & 3))*8;
  int r1 = c1 >> 2, g1 = ((c1 & 3) ^ (r1 & 3))*8;
  const u16* ga0 = A + (size_t)r0*DMODEL + g0;
  const u16* ga1 = A + (size_t)r1*DMODEL + g1;
  const u16* gb0 = W + (size_t)r0*DMODEL + g0;
  const u16* gb1 = W + (size_t)r1*DMODEL + g1;
  int sw = (quad ^ (r & 3))*8;               // de-swizzle for fragment reads

  auto stage = [&](int bu, int k0){
    u16* ab = abuf + bu*(128*32);
    u16* bb = bbuf + bu*(128*32);
    gload16(ga0 + k0, ab + c0*8);
    gload16(ga1 + k0, ab + c1*8);
    gload16(gb0 + k0, bb + c0*8);
    gload16(gb1 + k0, bb + c1*8);
  };
  auto step = [&](int bu){
    const u16* ab = abuf + bu*(128*32);
    const u16* bb = bbuf + bu*(128*32);
    bf16x8 af[4], bfr[4];
    #pragma unroll
    for (int i = 0; i < 4; ++i) af[i]  = ld8(&ab[(wm + i*16 + r)*32 + sw]);
    #pragma unroll
    for (int i = 0; i < 4; ++i) bfr[i] = ld8(&bb[(wn + i*16 + r)*32 + sw]);
    #pragma unroll
    for (int mi = 0; mi < 4; ++mi)
      #pragma unroll
      for (int ni = 0; ni < 4; ++ni)
        acc[mi][ni] = __builtin_amdgcn_mfma_f32_16x16x32_bf16(af[mi], bfr[ni], acc[mi][ni], 0,0,0);
  };

  stage(0, 0);
  __syncthreads();                           // prologue tile visible
  for (int k0 = 0; k0 < DMODEL; k0 += 64){
    stage(1, k0 + 32);                       // prefetch in flight over compute
    step(0);
    __syncthreads();                         // drains vmcnt: buf1 staged, buf0 reads done
    if (k0 + 64 < DMODEL) stage(0, k0 + 64);
    step(1);
    __syncthreads();
  }
}

// QKV projection: grid (32, 24). q,k -> (B,H,S,DK); v -> transposed (B,H,DK,S)
__global__ __launch_bounds__(256) void qkv_proj_kernel(
    const u16* __restrict__ xq, const u16* __restrict__ xk, const u16* __restrict__ xv,
    const u16* __restrict__ w, const float* __restrict__ bias,
    u16* __restrict__ q_ws, u16* __restrict__ k_ws, u16* __restrict__ vt_ws)
{
  __shared__ __align__(16) u16 abuf[2*128*32];
  __shared__ __align__(16) u16 bbuf[2*128*32];
  int tid = threadIdx.x;
  int lane = tid & 63, quad = lane >> 4, r = lane & 15;
  int wv = tid >> 6, wm = (wv & 1)*64, wn = (wv >> 1)*64;
  int m0 = blockIdx.x*128, n0 = blockIdx.y*128;
  int t = n0 >> 10;                          // 0=q,1=k,2=v (block-uniform; 1024%128==0)
  const u16* X = (t == 0) ? xq : (t == 1) ? xk : xv;

  f32x4 acc[4][4] = {};
  gemm128_loop(X + (size_t)m0*DMODEL, w + (size_t)n0*DMODEL, abuf, bbuf, tid, acc);

  int mbase = m0 + wm, nbase = n0 + wn;
  #pragma unroll
  for (int ni = 0; ni < 4; ++ni){
    int n  = nbase + ni*16 + r;
    float bv = bias[n];
    int nn = n & (DMODEL-1);
    int h = nn >> 6, dk = nn & 63;
    #pragma unroll
    for (int mi = 0; mi < 4; ++mi){
      #pragma unroll
      for (int reg = 0; reg < 4; ++reg){
        int m = mbase + mi*16 + quad*4 + reg;
        int s = m >> 1, b = m & 1;           // m = s*B + b
        u16 hv = f2bf(acc[mi][ni][reg] + bv);
        size_t bh = (size_t)(b*NHEADS + h);
        if (t == 0)      q_ws [(bh*S_LEN + s)*DKH + dk] = hv;
        else if (t == 1) k_ws [(bh*S_LEN + s)*DKH + dk] = hv;
        else             vt_ws[(bh*DKH + dk)*S_LEN + s] = hv;
      }
    }
  }
}

// Flash attention.
//  - XCD-aware bijective remap: 4 heads per XCD (KV working set 2MB < 4MB L2)
//    instead of each head's blocks round-robining over all 8 XCDs.
//  - 2-phase LDS double-buffer + T14 async-STAGE: store tile t+1 regs and
//    issue tile t+2 global loads while computing tile t; ONE barrier/tile.
//  - T5 s_setprio(1) around the QK^T and PV MFMA clusters (+4-7% attested).
// Math/layouts identical to the last harness-verified version.
__global__ __launch_bounds__(256) void attn_kernel(
    const u16* __restrict__ q_ws, const u16* __restrict__ k_ws, const u16* __restrict__ vt_ws,
    const u64* __restrict__ mbits, u16* __restrict__ x_ws)
{
  __shared__ __align__(16) u16 kbuf[2][64*72];
  __shared__ __align__(16) u16 vbuf[2][64*72];
  __shared__ __align__(16) u16 pbuf[4][16*72];
  int tid  = threadIdx.x;
  int wv   = tid >> 6;
  int lane = tid & 63;
  int quad = lane >> 4, r = lane & 15;

  // bijective XCD swizzle: lin -> (xcd, slot); 4 bh x 32 xt per XCD
  int lin  = blockIdx.y * 32 + blockIdx.x;   // grid (32,32) = 1024
  int xcd  = lin & 7, slot = lin >> 3;
  int bh   = (xcd << 2) | (slot >> 5);
  int xt   = slot & 31;
  int b  = bh >> 4, h = bh & 15;
  int i0 = (xt*4 + wv) * 16;

  const u16* Q  = q_ws  + (size_t)bh*S_LEN*DKH;
  const u16* K  = k_ws  + (size_t)bh*S_LEN*DKH;
  const u16* Vt = vt_ws + (size_t)bh*DKH*S_LEN;
  const u64* MB = mbits + ((size_t)b*S_LEN + (i0 + r))*MWORDS;

  int f1 = tid + 256;
  int sr0 = tid >> 3, sc0 = (tid & 7)*8;
  int sr1 = f1  >> 3, sc1 = (f1  & 7)*8;

  const u16* qrow = Q + (size_t)(i0 + r)*DKH + quad*8;
  bf16x8 qf0 = ld8(qrow), qf1 = ld8(qrow + 32);

  float l_part = 0.f;
  f32x4 o[4] = {};
  f32x4 z = {0.f, 0.f, 0.f, 0.f};
  u16* pl = pbuf[wv];

  bf16x8 ak0, ak1, av0, av1, bk0, bk1, bv0, bv1;

  auto loadset = [&](bf16x8& kv0, bf16x8& kv1, bf16x8& vv0, bf16x8& vv1, int j0){
    kv0 = ld8(K  + (size_t)(j0 + sr0)*DKH + sc0);
    kv1 = ld8(K  + (size_t)(j0 + sr1)*DKH + sc1);
    vv0 = ld8(Vt + (size_t)sr0*S_LEN + j0 + sc0);
    vv1 = ld8(Vt + (size_t)sr1*S_LEN + j0 + sc1);
  };
  auto storeset = [&](u16* kb, u16* vb, bf16x8 kv0, bf16x8 kv1, bf16x8 vv0, bf16x8 vv1){
    *(bf16x8*)&kb[sr0*72 + sc0] = kv0;
    *(bf16x8*)&kb[sr1*72 + sc1] = kv1;
    *(bf16x8*)&vb[sr0*72 + sc0] = vv0;
    *(bf16x8*)&vb[sr1*72 + sc1] = vv1;
  };
  auto compute = [&](const u16* kb, const u16* vb, u64 mb){
    float p[16];
    #pragma unroll
    for (int c = 0; c < 4; ++c){
      bf16x8 ka = ld8(&kb[(16*c + r)*72 + quad*8]);
      bf16x8 k8 = ld8(&kb[(16*c + r)*72 + 32 + quad*8]);
      __builtin_amdgcn_s_setprio(1);
      f32x4 s = __builtin_amdgcn_mfma_f32_16x16x32_bf16(ka, qf0, z, 0,0,0);
      s       = __builtin_amdgcn_mfma_f32_16x16x32_bf16(k8, qf1, s, 0,0,0);
      __builtin_amdgcn_s_setprio(0);
      u32 mc = (u32)(mb >> (16*c + 4*quad));
      p[c*4+0] = (mc & 1u) ? 0.f : __expf(s[0]*ATT_SCALE);
      p[c*4+1] = (mc & 2u) ? 0.f : __expf(s[1]*ATT_SCALE);
      p[c*4+2] = (mc & 4u) ? 0.f : __expf(s[2]*ATT_SCALE);
      p[c*4+3] = (mc & 8u) ? 0.f : __expf(s[3]*ATT_SCALE);
      l_part += p[c*4+0] + p[c*4+1] + p[c*4+2] + p[c*4+3];
    }
    #pragma unroll
    for (int c = 0; c < 4; ++c)
      *(ushort4*)&pl[r*72 + 16*c + quad*4] =
        make_ushort4(f2bf(p[c*4+0]), f2bf(p[c*4+1]), f2bf(p[c*4+2]), f2bf(p[c*4+3]));
    asm volatile("s_waitcnt lgkmcnt(0)" ::: "memory");
    bf16x8 pf0 = ld8(&pl[r*72 + quad*8]);
    bf16x8 pf1 = ld8(&pl[r*72 + 32 + quad*8]);
    __builtin_amdgcn_s_setprio(1);
    #pragma unroll
    for (int tt = 0; tt < 4; ++tt){
      bf16x8 va = ld8(&vb[(tt*16 + r)*72 + quad*8]);
      bf16x8 v8 = ld8(&vb[(tt*16 + r)*72 + 32 + quad*8]);
      o[tt] = __builtin_amdgcn_mfma_f32_16x16x32_bf16(pf0, va, o[tt], 0,0,0);
      o[tt] = __builtin_amdgcn_mfma_f32_16x16x32_bf16(pf1, v8, o[tt], 0,0,0);
    }
    __builtin_amdgcn_s_setprio(0);
  };

  // prologue: tile0 -> buf0 (vmcnt wait folds into the ds_write deps),
  // tile1 loads in flight into b-set.
  loadset(ak0, ak1, av0, av1, 0);
  storeset(kbuf[0], vbuf[0], ak0, ak1, av0, av1);
  loadset(bk0, bk1, bv0, bv1, 64);
  __syncthreads();

  for (int j0 = 0; j0 < S_LEN; j0 += 128){
    // tile j0 ready in buf0; b-set holds j0+64
    storeset(kbuf[1], vbuf[1], bk0, bk1, bv0, bv1);
    if (j0 + 128 < S_LEN) loadset(ak0, ak1, av0, av1, j0 + 128);
    compute(kbuf[0], vbuf[0], MB[j0 >> 6]);
    __syncthreads();                         // buf1 stores visible; buf0 reads done
    // tile j0+64 ready in buf1; a-set holds j0+128 (if any)
    if (j0 + 128 < S_LEN) storeset(kbuf[0], vbuf[0], ak0, ak1, av0, av1);
    if (j0 + 192 < S_LEN) loadset(bk0, bk1, bv0, bv1, j0 + 192);
    compute(kbuf[1], vbuf[1], MB[(j0 >> 6) + 1]);
    __syncthreads();
  }

  l_part += __shfl_xor(l_part, 16, 64);
  l_part += __shfl_xor(l_part, 32, 64);
  float l0 = 1.f/__shfl(l_part, quad*4+0, 64);
  float l1 = 1.f/__shfl(l_part, quad*4+1, 64);
  float l2 = 1.f/__shfl(l_part, quad*4+2, 64);
  float l3 = 1.f/__shfl(l_part, quad*4+3, 64);
  #pragma unroll
  for (int tt = 0; tt < 4; ++tt){
    int col = h*DKH + tt*16 + r;
    x_ws[((size_t)(i0 + quad*4 + 0)*BATCH + b)*DMODEL + col] = f2bf(o[tt][0]*l0);
    x_ws[((size_t)(i0 + quad*4 + 1)*BATCH + b)*DMODEL + col] = f2bf(o[tt][1]*l1);
    x_ws[((size_t)(i0 + quad*4 + 2)*BATCH + b)*DMODEL + col] = f2bf(o[tt][2]*l2);
    x_ws[((size_t)(i0 + quad*4 + 3)*BATCH + b)*DMODEL + col] = f2bf(o[tt][3]*l3);
  }
}

// Out projection: grid (32, 8). x_ws(bf16) @ Wout.T(bf16) + bout -> fp32
__global__ __launch_bounds__(256) void out_proj_kernel(
    const u16* __restrict__ x, const u16* __restrict__ w, const float* __restrict__ bias,
    float* __restrict__ out)
{
  __shared__ __align__(16) u16 abuf[2*128*32];
  __shared__ __align__(16) u16 bbuf[2*128*32];
  int tid = threadIdx.x;
  int lane = tid & 63, quad = lane >> 4, r = lane & 15;
  int wv = tid >> 6, wm = (wv & 1)*64, wn = (wv >> 1)*64;
  int m0 = blockIdx.x*128, n0 = blockIdx.y*128;

  f32x4 acc[4][4] = {};
  gemm128_loop(x + (size_t)m0*DMODEL, w + (size_t)n0*DMODEL, abuf, bbuf, tid, acc);

  int mbase = m0 + wm, nbase = n0 + wn;
  #pragma unroll
  for (int ni = 0; ni < 4; ++ni){
    int n = nbase + ni*16 + r;
    float bv = bias[n];
    #pragma unroll
    for (int mi = 0; mi < 4; ++mi){
      #pragma unroll
      for (int reg = 0; reg < 4; ++reg){
        int m = mbase + mi*16 + quad*4 + reg;
        out[(size_t)m*DMODEL + n] = acc[mi][ni][reg] + bv;
      }
    }
  }
}

extern "C" void kernel_launch(void* const* d_in, const int* in_sizes, int n_in,
                              void* d_out, int out_size, void* d_ws, size_t ws_size,
                              hipStream_t stream) {
  (void)in_sizes; (void)n_in; (void)out_size; (void)ws_size;
  const float* query = (const float*)d_in[0];
  const float* key   = (const float*)d_in[1];
  const float* value = (const float*)d_in[2];
  const int*   mask  = (const int*)d_in[3];
  const float* w_in  = (const float*)d_in[4];
  const float* b_in  = (const float*)d_in[5];
  const float* w_out = (const float*)d_in[6];
  const float* b_out = (const float*)d_in[7];
  float* out = (float*)d_out;

  const size_t TSZ = (size_t)BATCH*NHEADS*S_LEN*DKH;
  const size_t XSZ = (size_t)S_LEN*BATCH*DMODEL;
  u16* q_ws  = (u16*)d_ws;
  u16* k_ws  = q_ws  + TSZ;
  u16* vt_ws = k_ws  + TSZ;
  u16* x_ws  = vt_ws + TSZ;
  u16* xq_bf = x_ws  + XSZ;
  u16* xk_bf = xq_bf + XSZ;
  u16* xv_bf = xk_bf + XSZ;
  u16* wi_bf = xv_bf + XSZ;
  u16* wo_bf = wi_bf + (size_t)3*DMODEL*DMODEL;
  u64* mb_ws = (u64*)(wo_bf + (size_t)DMODEL*DMODEL);

  cvt_kernel<<<1024, 256, 0, stream>>>(query, key, value, w_in, w_out, mask,
                                       xq_bf, xk_bf, xv_bf, wi_bf, wo_bf, mb_ws);
  qkv_proj_kernel<<<dim3(32, 24), 256, 0, stream>>>(xq_bf, xk_bf, xv_bf, wi_bf, b_in,
                                                    q_ws, k_ws, vt_ws);
  attn_kernel<<<dim3(32, 32), 256, 0, stream>>>(q_ws, k_ws, vt_ws, mb_ws, x_ws);
  out_proj_kernel<<<dim3(32, 8), 256, 0, stream>>>(x_ws, wo_bf, b_out, out);
}

// Round 5
// 251.181 us; speedup vs baseline: 1.1507x; 1.1507x over previous
//
#include <hip/hip_runtime.h>
#include <hip/hip_bf16.h>

typedef unsigned short u16;
typedef unsigned int   u32;
typedef unsigned long long u64;
typedef __bf16 bf16x8 __attribute__((ext_vector_type(8)));
typedef float  f32x4  __attribute__((ext_vector_type(4)));

#define S_LEN  2048
#define BATCH  2
#define DMODEL 1024
#define NHEADS 16
#define DKH    64
#define MWORDS (S_LEN/64)
#define ATT_SCALE 0.125f

__device__ __forceinline__ u16 f2bf(float f){
  u32 x = __builtin_bit_cast(u32, f);
  x += 0x7fffu + ((x >> 16) & 1u);   // RNE
  return (u16)(x >> 16);
}
__device__ __forceinline__ bf16x8 ld8(const u16* p){ return *(const bf16x8*)p; }

// v_cvt_pk_bf16_f32: D[15:0]=bf16(S0), D[31:16]=bf16(S1), RNE — bit-identical
// to f2bf pairs, 1 instruction instead of ~10.
__device__ __forceinline__ u32 pk_bf16(float a, float b){
  u32 d;
  asm("v_cvt_pk_bf16_f32 %0, %1, %2" : "=v"(d) : "v"(a), "v"(b));
  return d;
}

// async global->LDS, 16B per lane. HW: dest = wave-uniform base + lane*16.
__device__ __forceinline__ void gload16(const u16* g, u16* l){
  __builtin_amdgcn_global_load_lds(
      (const __attribute__((address_space(1))) u32*)(u64)g,
      (__attribute__((address_space(3))) u32*)(u64)l,
      16, 0, 0);
}

// ---- fp32->bf16 bulk conversion + mask bit-packing (unchanged, passing) ----
__global__ __launch_bounds__(256) void cvt_kernel(
    const float* __restrict__ a0, const float* __restrict__ a1, const float* __restrict__ a2,
    const float* __restrict__ wi, const float* __restrict__ wo, const int* __restrict__ msk,
    u16* __restrict__ d0, u16* __restrict__ d1, u16* __restrict__ d2,
    u16* __restrict__ dwi, u16* __restrict__ dwo, u64* __restrict__ mbits)
{
  int tid = blockIdx.x*256 + threadIdx.x;
  int stride = gridDim.x*256;
  const int NX = S_LEN*BATCH*DMODEL/4;
  for (int i = tid; i < NX; i += stride){
    f32x4 x0 = ((const f32x4*)a0)[i];
    f32x4 x1 = ((const f32x4*)a1)[i];
    f32x4 x2 = ((const f32x4*)a2)[i];
    ((ushort4*)d0)[i] = make_ushort4(f2bf(x0[0]), f2bf(x0[1]), f2bf(x0[2]), f2bf(x0[3]));
    ((ushort4*)d1)[i] = make_ushort4(f2bf(x1[0]), f2bf(x1[1]), f2bf(x1[2]), f2bf(x1[3]));
    ((ushort4*)d2)[i] = make_ushort4(f2bf(x2[0]), f2bf(x2[1]), f2bf(x2[2]), f2bf(x2[3]));
  }
  const int NWI = 3*DMODEL*DMODEL/4;
  for (int i = tid; i < NWI; i += stride){
    f32x4 x = ((const f32x4*)wi)[i];
    ((ushort4*)dwi)[i] = make_ushort4(f2bf(x[0]), f2bf(x[1]), f2bf(x[2]), f2bf(x[3]));
  }
  const int NWO = DMODEL*DMODEL/4;
  for (int i = tid; i < NWO; i += stride){
    f32x4 x = ((const f32x4*)wo)[i];
    ((ushort4*)dwo)[i] = make_ushort4(f2bf(x[0]), f2bf(x[1]), f2bf(x[2]), f2bf(x[3]));
  }
  int gw   = tid >> 6;
  int lane = threadIdx.x & 63;
  int nwaves = stride >> 6;
  const int NW = BATCH*S_LEN*MWORDS;
  for (int w4 = gw*4; w4 < NW; w4 += nwaves*4){
    int v0 = msk[(size_t)(w4+0)*64 + lane];
    int v1 = msk[(size_t)(w4+1)*64 + lane];
    int v2 = msk[(size_t)(w4+2)*64 + lane];
    int v3 = msk[(size_t)(w4+3)*64 + lane];
    u64 b0 = __ballot(v0 != 0);
    u64 b1 = __ballot(v1 != 0);
    u64 b2 = __ballot(v2 != 0);
    u64 b3 = __ballot(v3 != 0);
    if (lane == 0){
      mbits[w4+0] = b0; mbits[w4+1] = b1;
      mbits[w4+2] = b2; mbits[w4+3] = b3;
    }
  }
}

// ---- 128x128 block GEMM mainloop (C = A @ W^T), K = DMODEL ----
// 2-phase LDS double-buffer; unchanged from the passing round-2 version.
__device__ __forceinline__ void gemm128_loop(
    const u16* __restrict__ A, const u16* __restrict__ W,
    u16* abuf, u16* bbuf, int tid, f32x4 acc[4][4])
{
  int lane = tid & 63, quad = lane >> 4, r = lane & 15;
  int wv = tid >> 6, wm = (wv & 1)*64, wn = (wv >> 1)*64;
  int c0 = tid, c1 = tid + 256;              // 16B-chunk ids (512 per tile)
  int r0 = c0 >> 2, g0 = ((c0 & 3) ^ (r0 & 3))*8;
  int r1 = c1 >> 2, g1 = ((c1 & 3) ^ (r1 & 3))*8;
  const u16* ga0 = A + (size_t)r0*DMODEL + g0;
  const u16* ga1 = A + (size_t)r1*DMODEL + g1;
  const u16* gb0 = W + (size_t)r0*DMODEL + g0;
  const u16* gb1 = W + (size_t)r1*DMODEL + g1;
  int sw = (quad ^ (r & 3))*8;               // de-swizzle for fragment reads

  auto stage = [&](int bu, int k0){
    u16* ab = abuf + bu*(128*32);
    u16* bb = bbuf + bu*(128*32);
    gload16(ga0 + k0, ab + c0*8);
    gload16(ga1 + k0, ab + c1*8);
    gload16(gb0 + k0, bb + c0*8);
    gload16(gb1 + k0, bb + c1*8);
  };
  auto step = [&](int bu){
    const u16* ab = abuf + bu*(128*32);
    const u16* bb = bbuf + bu*(128*32);
    bf16x8 af[4], bfr[4];
    #pragma unroll
    for (int i = 0; i < 4; ++i) af[i]  = ld8(&ab[(wm + i*16 + r)*32 + sw]);
    #pragma unroll
    for (int i = 0; i < 4; ++i) bfr[i] = ld8(&bb[(wn + i*16 + r)*32 + sw]);
    #pragma unroll
    for (int mi = 0; mi < 4; ++mi)
      #pragma unroll
      for (int ni = 0; ni < 4; ++ni)
        acc[mi][ni] = __builtin_amdgcn_mfma_f32_16x16x32_bf16(af[mi], bfr[ni], acc[mi][ni], 0,0,0);
  };

  stage(0, 0);
  __syncthreads();                           // prologue tile visible
  for (int k0 = 0; k0 < DMODEL; k0 += 64){
    stage(1, k0 + 32);                       // prefetch in flight over compute
    step(0);
    __syncthreads();                         // drains vmcnt: buf1 staged, buf0 reads done
    if (k0 + 64 < DMODEL) stage(0, k0 + 64);
    step(1);
    __syncthreads();
  }
}

// QKV projection: grid (32, 24). q,k -> (B,H,S,DK); v -> transposed (B,H,DK,S)
__global__ __launch_bounds__(256) void qkv_proj_kernel(
    const u16* __restrict__ xq, const u16* __restrict__ xk, const u16* __restrict__ xv,
    const u16* __restrict__ w, const float* __restrict__ bias,
    u16* __restrict__ q_ws, u16* __restrict__ k_ws, u16* __restrict__ vt_ws)
{
  __shared__ __align__(16) u16 abuf[2*128*32];
  __shared__ __align__(16) u16 bbuf[2*128*32];
  int tid = threadIdx.x;
  int lane = tid & 63, quad = lane >> 4, r = lane & 15;
  int wv = tid >> 6, wm = (wv & 1)*64, wn = (wv >> 1)*64;
  int m0 = blockIdx.x*128, n0 = blockIdx.y*128;
  int t = n0 >> 10;                          // 0=q,1=k,2=v (block-uniform; 1024%128==0)
  const u16* X = (t == 0) ? xq : (t == 1) ? xk : xv;

  f32x4 acc[4][4] = {};
  gemm128_loop(X + (size_t)m0*DMODEL, w + (size_t)n0*DMODEL, abuf, bbuf, tid, acc);

  int mbase = m0 + wm, nbase = n0 + wn;
  #pragma unroll
  for (int ni = 0; ni < 4; ++ni){
    int n  = nbase + ni*16 + r;
    float bv = bias[n];
    int nn = n & (DMODEL-1);
    int h = nn >> 6, dk = nn & 63;
    #pragma unroll
    for (int mi = 0; mi < 4; ++mi){
      #pragma unroll
      for (int reg = 0; reg < 4; ++reg){
        int m = mbase + mi*16 + quad*4 + reg;
        int s = m >> 1, b = m & 1;           // m = s*B + b
        u16 hv = f2bf(acc[mi][ni][reg] + bv);
        size_t bh = (size_t)(b*NHEADS + h);
        if (t == 0)      q_ws [(bh*S_LEN + s)*DKH + dk] = hv;
        else if (t == 1) k_ws [(bh*S_LEN + s)*DKH + dk] = hv;
        else             vt_ws[(bh*DKH + dk)*S_LEN + s] = hv;
      }
    }
  }
}

// Flash attention — reworked (bit-exact math, new layout/occupancy):
//  * 8 waves/block (512 thr), grid 512 = exactly 2 blocks/CU: kills the
//    1024-block/3-per-CU 25% tail; K/V staged once per 8 waves (was 4).
//  * LDS [64][64] unpadded + chunk-XOR swizzle (chunk' = chunk ^ (row&7)) on
//    BOTH write and read of kbuf/vbuf/pbuf (write-side and read-side use the
//    same involution; reg-staged ds_writes so swizzling is legal).
//  * P pack via v_cvt_pk_bf16_f32 (RNE, bit-identical to f2bf, ~8x fewer ops).
__global__ __launch_bounds__(512) void attn_kernel(
    const u16* __restrict__ q_ws, const u16* __restrict__ k_ws, const u16* __restrict__ vt_ws,
    const u64* __restrict__ mbits, u16* __restrict__ x_ws)
{
  __shared__ __align__(16) u16 kbuf[2][64*64];
  __shared__ __align__(16) u16 vbuf[2][64*64];
  __shared__ __align__(16) u16 pbuf[8][16*64];
  int tid  = threadIdx.x;
  int wv   = tid >> 6;                       // 0..7
  int lane = tid & 63;
  int quad = lane >> 4, r = lane & 15;

  // bijective XCD swizzle: 4 bh x 16 xt per XCD (KV set 2MB < 4MB L2)
  int lin  = blockIdx.y * 16 + blockIdx.x;   // grid (16,32) = 512
  int xcd  = lin & 7, slot = lin >> 3;       // slot 0..63
  int bh   = (xcd << 2) | (slot >> 4);
  int xt   = slot & 15;
  int b  = bh >> 4, h = bh & 15;
  int i0 = (xt*8 + wv) * 16;

  const u16* Q  = q_ws  + (size_t)bh*S_LEN*DKH;
  const u16* K  = k_ws  + (size_t)bh*S_LEN*DKH;
  const u16* Vt = vt_ws + (size_t)bh*DKH*S_LEN;
  const u64* MB = mbits + ((size_t)b*S_LEN + (i0 + r))*MWORDS;

  // staging: 512 threads x 16B = one full 64x64 tile per buffer
  int sr  = tid >> 3;                        // row 0..63
  int sc8 = (tid & 7) * 8;                   // logical element col
  int ssw = ((tid & 7) ^ (sr & 7)) * 8;      // swizzled element col
  const u16* Kp = K  + (size_t)sr*DKH   + sc8;
  const u16* Vp = Vt + (size_t)sr*S_LEN + sc8;

  const u16* qrow = Q + (size_t)(i0 + r)*DKH + quad*8;
  bf16x8 qf0 = ld8(qrow), qf1 = ld8(qrow + 32);

  // swizzled per-lane read offsets (element units)
  int m7   = r & 7;
  int ksw0 = (quad ^ m7) * 8;                // lo chunk
  int ksw1 = ksw0 ^ 32;                      // chunk^4 == +/-32 elements
  int pw0  = ((quad >> 1) ^ m7) * 8 + (quad & 1)*4;  // c=0 write base; c adds 2 to chunk

  float l_part = 0.f;
  f32x4 o[4] = {};
  f32x4 z = {0.f, 0.f, 0.f, 0.f};
  u16* pl = pbuf[wv];

  bf16x8 ka_, va_, kb_, vb_;
  auto loadset = [&](bf16x8& kv, bf16x8& vv, int j0){
    kv = ld8(Kp + (size_t)j0*DKH);
    vv = ld8(Vp + j0);
  };
  auto storeset = [&](int bu, bf16x8 kv, bf16x8 vv){
    *(bf16x8*)&kbuf[bu][sr*64 + ssw] = kv;
    *(bf16x8*)&vbuf[bu][sr*64 + ssw] = vv;
  };
  auto compute = [&](int bu, u64 mb){
    const u16* kb = kbuf[bu];
    const u16* vb = vbuf[bu];
    float p[16];
    #pragma unroll
    for (int c = 0; c < 4; ++c){
      int rowb = (16*c + r)*64;
      bf16x8 ka = ld8(&kb[rowb + ksw0]);
      bf16x8 k8 = ld8(&kb[rowb + ksw1]);
      __builtin_amdgcn_s_setprio(1);
      f32x4 s = __builtin_amdgcn_mfma_f32_16x16x32_bf16(ka, qf0, z, 0,0,0);
      s       = __builtin_amdgcn_mfma_f32_16x16x32_bf16(k8, qf1, s, 0,0,0);
      __builtin_amdgcn_s_setprio(0);
      u32 mc = (u32)(mb >> (16*c + 4*quad));
      p[c*4+0] = (mc & 1u) ? 0.f : __expf(s[0]*ATT_SCALE);
      p[c*4+1] = (mc & 2u) ? 0.f : __expf(s[1]*ATT_SCALE);
      p[c*4+2] = (mc & 4u) ? 0.f : __expf(s[2]*ATT_SCALE);
      p[c*4+3] = (mc & 8u) ? 0.f : __expf(s[3]*ATT_SCALE);
      l_part += p[c*4+0] + p[c*4+1] + p[c*4+2] + p[c*4+3];
    }
    // pack P rows: lane (r,quad) owns cols 16c+4q..+3; chunk = 2c+(q>>1),
    // swizzled ^ (r&7); within-chunk half = (q&1)*4 elements.
    #pragma unroll
    for (int c = 0; c < 4; ++c){
      u32 k0 = pk_bf16(p[c*4+0], p[c*4+1]);
      u32 k1 = pk_bf16(p[c*4+2], p[c*4+3]);
      // chunk 2c+(q>>1): XOR with m7 decomposes exactly — 2c occupies bits
      // 1-2, (q>>1) bit 0, so ((q>>1)^m7)^2c == (2c+(q>>1))^m7:
      *(uint2*)&pl[r*64 + ((pw0 & ~7) ^ (2*c*8)) + (pw0 & 7)] = make_uint2(k0, k1);
    }
    asm volatile("s_waitcnt lgkmcnt(0)" ::: "memory");
    bf16x8 pf0 = ld8(&pl[r*64 + ksw0]);      // logical chunk quad
    bf16x8 pf1 = ld8(&pl[r*64 + ksw1]);      // logical chunk quad+4
    __builtin_amdgcn_s_setprio(1);
    #pragma unroll
    for (int tt = 0; tt < 4; ++tt){
      int rowb = (tt*16 + r)*64;
      bf16x8 va = ld8(&vb[rowb + ksw0]);
      bf16x8 v8 = ld8(&vb[rowb + ksw1]);
      o[tt] = __builtin_amdgcn_mfma_f32_16x16x32_bf16(pf0, va, o[tt], 0,0,0);
      o[tt] = __builtin_amdgcn_mfma_f32_16x16x32_bf16(pf1, v8, o[tt], 0,0,0);
    }
    __builtin_amdgcn_s_setprio(0);
  };

  // prologue: tile0 staged to buf0; tile1 loads in flight
  loadset(ka_, va_, 0);
  storeset(0, ka_, va_);
  loadset(kb_, vb_, 64);
  __syncthreads();

  for (int j0 = 0; j0 < S_LEN; j0 += 128){
    storeset(1, kb_, vb_);
    if (j0 + 128 < S_LEN) loadset(ka_, va_, j0 + 128);
    compute(0, MB[j0 >> 6]);
    __syncthreads();                         // buf1 visible; buf0 reads done
    if (j0 + 128 < S_LEN) storeset(0, ka_, va_);
    if (j0 + 192 < S_LEN) loadset(kb_, vb_, j0 + 192);
    compute(1, MB[(j0 >> 6) + 1]);
    __syncthreads();
  }

  l_part += __shfl_xor(l_part, 16, 64);
  l_part += __shfl_xor(l_part, 32, 64);
  float l0 = 1.f/__shfl(l_part, quad*4+0, 64);
  float l1 = 1.f/__shfl(l_part, quad*4+1, 64);
  float l2 = 1.f/__shfl(l_part, quad*4+2, 64);
  float l3 = 1.f/__shfl(l_part, quad*4+3, 64);
  #pragma unroll
  for (int tt = 0; tt < 4; ++tt){
    int col = h*DKH + tt*16 + r;
    x_ws[((size_t)(i0 + quad*4 + 0)*BATCH + b)*DMODEL + col] = f2bf(o[tt][0]*l0);
    x_ws[((size_t)(i0 + quad*4 + 1)*BATCH + b)*DMODEL + col] = f2bf(o[tt][1]*l1);
    x_ws[((size_t)(i0 + quad*4 + 2)*BATCH + b)*DMODEL + col] = f2bf(o[tt][2]*l2);
    x_ws[((size_t)(i0 + quad*4 + 3)*BATCH + b)*DMODEL + col] = f2bf(o[tt][3]*l3);
  }
}

// Out projection: grid (32, 8). x_ws(bf16) @ Wout.T(bf16) + bout -> fp32
__global__ __launch_bounds__(256) void out_proj_kernel(
    const u16* __restrict__ x, const u16* __restrict__ w, const float* __restrict__ bias,
    float* __restrict__ out)
{
  __shared__ __align__(16) u16 abuf[2*128*32];
  __shared__ __align__(16) u16 bbuf[2*128*32];
  int tid = threadIdx.x;
  int lane = tid & 63, quad = lane >> 4, r = lane & 15;
  int wv = tid >> 6, wm = (wv & 1)*64, wn = (wv >> 1)*64;
  int m0 = blockIdx.x*128, n0 = blockIdx.y*128;

  f32x4 acc[4][4] = {};
  gemm128_loop(x + (size_t)m0*DMODEL, w + (size_t)n0*DMODEL, abuf, bbuf, tid, acc);

  int mbase = m0 + wm, nbase = n0 + wn;
  #pragma unroll
  for (int ni = 0; ni < 4; ++ni){
    int n = nbase + ni*16 + r;
    float bv = bias[n];
    #pragma unroll
    for (int mi = 0; mi < 4; ++mi){
      #pragma unroll
      for (int reg = 0; reg < 4; ++reg){
        int m = mbase + mi*16 + quad*4 + reg;
        out[(size_t)m*DMODEL + n] = acc[mi][ni][reg] + bv;
      }
    }
  }
}

extern "C" void kernel_launch(void* const* d_in, const int* in_sizes, int n_in,
                              void* d_out, int out_size, void* d_ws, size_t ws_size,
                              hipStream_t stream) {
  (void)in_sizes; (void)n_in; (void)out_size; (void)ws_size;
  const float* query = (const float*)d_in[0];
  const float* key   = (const float*)d_in[1];
  const float* value = (const float*)d_in[2];
  const int*   mask  = (const int*)d_in[3];
  const float* w_in  = (const float*)d_in[4];
  const float* b_in  = (const float*)d_in[5];
  const float* w_out = (const float*)d_in[6];
  const float* b_out = (const float*)d_in[7];
  float* out = (float*)d_out;

  const size_t TSZ = (size_t)BATCH*NHEADS*S_LEN*DKH;
  const size_t XSZ = (size_t)S_LEN*BATCH*DMODEL;
  u16* q_ws  = (u16*)d_ws;
  u16* k_ws  = q_ws  + TSZ;
  u16* vt_ws = k_ws  + TSZ;
  u16* x_ws  = vt_ws + TSZ;
  u16* xq_bf = x_ws  + XSZ;
  u16* xk_bf = xq_bf + XSZ;
  u16* xv_bf = xk_bf + XSZ;
  u16* wi_bf = xv_bf + XSZ;
  u16* wo_bf = wi_bf + (size_t)3*DMODEL*DMODEL;
  u64* mb_ws = (u64*)(wo_bf + (size_t)DMODEL*DMODEL);

  cvt_kernel<<<1024, 256, 0, stream>>>(query, key, value, w_in, w_out, mask,
                                       xq_bf, xk_bf, xv_bf, wi_bf, wo_bf, mb_ws);
  qkv_proj_kernel<<<dim3(32, 24), 256, 0, stream>>>(xq_bf, xk_bf, xv_bf, wi_bf, b_in,
                                                    q_ws, k_ws, vt_ws);
  attn_kernel<<<dim3(16, 32), 512, 0, stream>>>(q_ws, k_ws, vt_ws, mb_ws, x_ws);
  out_proj_kernel<<<dim3(32, 8), 256, 0, stream>>>(x_ws, wo_bf, b_out, out);
}